// Round 11
// baseline (944.777 us; speedup 1.0000x reference)
//
#include <hip/hip_runtime.h>
#include <stdint.h>

#define B_N   8
#define C_N   256
#define H_N   96
#define W_N   128
#define NCK   8          // C_N / 32
#define ND    21
#define NK    (ND * ND)  // 441

typedef __attribute__((ext_vector_type(8))) short short8;
typedef __attribute__((ext_vector_type(4))) float f32x4;

// 12-KB zero block (.bss) for OOB dy rows
__device__ char zchunk[12288];

__device__ __forceinline__ uint32_t f2bf(float f) {
  uint32_t u = __builtin_bit_cast(uint32_t, f);
  return (u + 0x7fffu + ((u >> 16) & 1u)) >> 16;   // RNE
}
__device__ __forceinline__ uint32_t packbf(float lo, float hi) {
  return f2bf(lo) | (f2bf(hi) << 16);
}

// ---------------- merged prepass: fp32 NCHW -> bf16 fragment-linear layouts ----------------
__global__ __launch_bounds__(256) void prep(const float* __restrict__ in1,
                                            const float* __restrict__ in2,
                                            unsigned short* __restrict__ Apre,
                                            unsigned short* __restrict__ Bpre) {
  __shared__ float tile[32][W_N + 1];
  int blk = blockIdx.x;
  bool isA = blk < 6144;
  int rblk = isA ? blk : blk - 6144;
  int ck = rblk & 7, bi = rblk >> 3;
  int b = bi / H_N, row = bi % H_N;
  const float* src = (isA ? in1 : in2) + ((size_t)(b * C_N + ck * 32) * H_N + row) * W_N;
  int tid = threadIdx.x;
  for (int idx = tid; idx < 32 * W_N; idx += 256) {
    int c = idx >> 7, j = idx & 127;
    tile[c][j] = src[(size_t)c * (H_N * W_N) + j];
  }
  __syncthreads();
  if (isA) {
    uint32_t* dst = (uint32_t*)Apre + (size_t)rblk * 2048;
    for (int q = tid; q < 2048; q += 256) {
      int e2 = q & 3, ln = (q >> 2) & 63, tp = q >> 8;
      int t = tp >> 1, p = tp & 1;
      int m = ln & 15, kg = ln >> 4;
      int c0 = kg * 8 + 2 * e2;
      int j = 32 * t + 2 * m + p;
      dst[q] = packbf(tile[c0][j], tile[c0 + 1][j]);
    }
  } else {
    uint32_t* dst = (uint32_t*)Bpre + (size_t)rblk * 3072;
    for (int q = tid; q < 3072; q += 256) {
      int e2 = q & 3, ln = (q >> 2) & 63, sp = q >> 8;
      int s = sp >> 1, p = sp & 1;
      int m = ln & 15, kg = ln >> 4;
      int c0 = kg * 8 + 2 * e2;
      int x = 32 * s + 2 * m - 20 + p;
      dst[q] = ((unsigned)x < 128u) ? packbf(tile[c0][x], tile[c0 + 1][x]) : 0u;
    }
  }
}

// ---- fragment set / load / compute (R5 verbatim) ----
#define DECL_FRAGS(F) short8 F##_a0, F##_a1, F##_bb0, F##_bb1, F##_bb2, F##_bb3, \
                             F##_bb4, F##_bb5, F##_bb6, F##_bb7, F##_bb8, F##_bb9, F##_bb10, F##_bb11

#define LOADF(F, CK) do {                                                        \
  F##_a0 = *(const short8*)(Ap + (size_t)(CK) * 8192);                           \
  F##_a1 = *(const short8*)(Ap + (size_t)(CK) * 8192 + 2048);                    \
  F##_bb0  = *(const short8*)(Bp0 + (size_t)(CK) * bstr0 + 0 * 2048);            \
  F##_bb1  = *(const short8*)(Bp1 + (size_t)(CK) * bstr1 + 0 * 2048);            \
  F##_bb2  = *(const short8*)(Bp2 + (size_t)(CK) * bstr2 + 0 * 2048);            \
  F##_bb3  = *(const short8*)(Bp0 + (size_t)(CK) * bstr0 + 1 * 2048);            \
  F##_bb4  = *(const short8*)(Bp1 + (size_t)(CK) * bstr1 + 1 * 2048);            \
  F##_bb5  = *(const short8*)(Bp2 + (size_t)(CK) * bstr2 + 1 * 2048);            \
  F##_bb6  = *(const short8*)(Bp0 + (size_t)(CK) * bstr0 + 2 * 2048);            \
  F##_bb7  = *(const short8*)(Bp1 + (size_t)(CK) * bstr1 + 2 * 2048);            \
  F##_bb8  = *(const short8*)(Bp2 + (size_t)(CK) * bstr2 + 2 * 2048);            \
  F##_bb9  = *(const short8*)(Bp0 + (size_t)(CK) * bstr0 + 3 * 2048);            \
  F##_bb10 = *(const short8*)(Bp1 + (size_t)(CK) * bstr1 + 3 * 2048);            \
  F##_bb11 = *(const short8*)(Bp2 + (size_t)(CK) * bstr2 + 3 * 2048);            \
} while (0)

#define MF(a, b, c) __builtin_amdgcn_mfma_f32_16x16x32_bf16(a, b, c, 0, 0, 0)
#define COMPUTE(F) do {                                                          \
  acc[0][0][0] = MF(F##_a0, F##_bb0,  acc[0][0][0]);                             \
  acc[0][1][0] = MF(F##_a0, F##_bb1,  acc[0][1][0]);                             \
  acc[0][2][0] = MF(F##_a0, F##_bb2,  acc[0][2][0]);                             \
  acc[0][0][1] = MF(F##_a0, F##_bb3,  acc[0][0][1]);                             \
  acc[1][0][0] = MF(F##_a1, F##_bb3,  acc[1][0][0]);                             \
  acc[0][1][1] = MF(F##_a0, F##_bb4,  acc[0][1][1]);                             \
  acc[1][1][0] = MF(F##_a1, F##_bb4,  acc[1][1][0]);                             \
  acc[0][2][1] = MF(F##_a0, F##_bb5,  acc[0][2][1]);                             \
  acc[1][2][0] = MF(F##_a1, F##_bb5,  acc[1][2][0]);                             \
  acc[0][0][2] = MF(F##_a0, F##_bb6,  acc[0][0][2]);                             \
  acc[1][0][1] = MF(F##_a1, F##_bb6,  acc[1][0][1]);                             \
  acc[0][1][2] = MF(F##_a0, F##_bb7,  acc[0][1][2]);                             \
  acc[1][1][1] = MF(F##_a1, F##_bb7,  acc[1][1][1]);                             \
  acc[0][2][2] = MF(F##_a0, F##_bb8,  acc[0][2][2]);                             \
  acc[1][2][1] = MF(F##_a1, F##_bb8,  acc[1][2][1]);                             \
  acc[1][0][2] = MF(F##_a1, F##_bb9,  acc[1][0][2]);                             \
  acc[1][1][2] = MF(F##_a1, F##_bb10, acc[1][1][2]);                             \
  acc[1][2][2] = MF(F##_a1, F##_bb11, acc[1][2][2]);                             \
} while (0)

#define SB() __builtin_amdgcn_sched_barrier(0)

#define PIPELINE8()                                                              \
  LOADF(fA, 0); LOADF(fB, 1); SB();                                              \
  COMPUTE(fA); LOADF(fA, 2); SB();                                               \
  COMPUTE(fB); LOADF(fB, 3); SB();                                               \
  COMPUTE(fA); LOADF(fA, 4); SB();                                               \
  COMPUTE(fB); LOADF(fB, 5); SB();                                               \
  COMPUTE(fA); LOADF(fA, 6); SB();                                               \
  COMPUTE(fB); LOADF(fB, 7); SB();                                               \
  COMPUTE(fA); SB();                                                             \
  COMPUTE(fB);

// B-row pointer setup for row i (chunk-0 base + stride)
#define SETUP_BPTRS(IVAR)                                                        \
  {                                                                              \
    int y0 = (IVAR) + 2 * dyb - 20;                                              \
    _Pragma("unroll")                                                            \
    for (int g = 0; g < 3; ++g) {                                                \
      int y = y0 + 2 * g;                                                        \
      bool v = (unsigned)y < (unsigned)H_N;                                      \
      const char* base = v ? (const char*)Bpre + (size_t)(b * H_N + y) * 98304   \
                           : (const char*)zchunk;                                \
      const char* bp = base + ((4 * th + p) << 10) + lane * 16;                  \
      int bs = v ? 12288 : 0;                                                    \
      if (g == 0) { Bp0 = bp; bstr0 = bs; }                                      \
      else if (g == 1) { Bp1 = bp; bstr1 = bs; }                                 \
      else { Bp2 = bp; bstr2 = bs; }                                             \
    }                                                                            \
  }

// ---------------- real kernel: R5 fused (best known, ~145 us, passes) ----------------
__global__ __launch_bounds__(256, 1) void corr_fused(const unsigned short* __restrict__ Apre,
                                                     const unsigned short* __restrict__ Bpre,
                                                     float* __restrict__ out) {
  __shared__ float outl[ND][W_N + 1];
  int h = blockIdx.x;
  int l = (h & 7) * 672 + (h >> 3);
  int c = l / 7, q = l - 7 * c;
  int b = c / 96, i0 = c - 96 * b;
  int gidx = 6 - q;
  int i = i0 + 6 * q; if (i >= H_N) i -= H_N;
  int bi = b * H_N + i;
  int dyb = gidx * 3;
  int tid = threadIdx.x;
  int lane = tid & 63, w = tid >> 6;
  int p = w & 1, th = w >> 1;
  int m = lane & 15, kg = lane >> 4;
  f32x4 acc[2][3][3];
#pragma unroll
  for (int a0i = 0; a0i < 2; ++a0i)
#pragma unroll
    for (int a1i = 0; a1i < 3; ++a1i)
#pragma unroll
      for (int a2i = 0; a2i < 3; ++a2i) acc[a0i][a1i][a2i] = {0.f, 0.f, 0.f, 0.f};
  const char* Ap = (const char*)Apre + (size_t)bi * 65536 + ((4 * th + p) << 10) + lane * 16;
  const char* Bp0; const char* Bp1; const char* Bp2;
  int bstr0, bstr1, bstr2;
  SETUP_BPTRS(i)
  DECL_FRAGS(fA);
  DECL_FRAGS(fB);
  PIPELINE8()
#pragma unroll
  for (int g = 0; g < 3; ++g) {
    __syncthreads();
#pragma unroll
    for (int tt = 0; tt < 2; ++tt) {
      int t = 2 * th + tt;
#pragma unroll
      for (int dl = 0; dl < 3; ++dl) {
#pragma unroll
        for (int r = 0; r < 4; ++r) {
          int a_ = kg * 4 + r;
          int dxi = 16 * dl + m - a_;
          if (dxi >= 0 && dxi <= 20) {
            int j = 2 * (16 * t + a_) + p;
            outl[dxi][j] = acc[tt][g][dl][r];
          }
        }
      }
    }
    __syncthreads();
    int dyi = dyb + g;
    size_t obase = ((size_t)(b * NK + dyi * ND) * H_N + i) * W_N;
    for (int idx = tid; idx < ND * W_N; idx += 256) {
      int dxi = idx >> 7, j = idx & 127;
      out[obase + (size_t)dxi * (H_N * W_N) + j] = outl[dxi][j];
    }
  }
}

// ---------------- PROBE: 4x K-loop (distinct rows per pass -> real traffic) ----------------
__global__ __launch_bounds__(256, 1) void probe_k4(const unsigned short* __restrict__ Apre,
                                                   const unsigned short* __restrict__ Bpre,
                                                   float* __restrict__ scr) {
  int h = blockIdx.x;
  int l = (h & 7) * 672 + (h >> 3);
  int c = l / 7, q = l - 7 * c;
  int b = c / 96, i0 = c - 96 * b;
  int gidx = 6 - q;
  int ibase = i0 + 6 * q; if (ibase >= H_N) ibase -= H_N;
  int dyb = gidx * 3;
  int tid = threadIdx.x;
  int lane = tid & 63, w = tid >> 6;
  int p = w & 1, th = w >> 1;
  f32x4 acc[2][3][3];
#pragma unroll
  for (int a0i = 0; a0i < 2; ++a0i)
#pragma unroll
    for (int a1i = 0; a1i < 3; ++a1i)
#pragma unroll
      for (int a2i = 0; a2i < 3; ++a2i) acc[a0i][a1i][a2i] = {0.f, 0.f, 0.f, 0.f};
  DECL_FRAGS(fA);
  DECL_FRAGS(fB);
  for (int r = 0; r < 4; ++r) {
    int i = ibase + 24 * r; if (i >= H_N) i -= H_N;
    int bi = b * H_N + i;
    const char* Ap = (const char*)Apre + (size_t)bi * 65536 + ((4 * th + p) << 10) + lane * 16;
    const char* Bp0; const char* Bp1; const char* Bp2;
    int bstr0, bstr1, bstr2;
    SETUP_BPTRS(i)
    PIPELINE8()
  }
  float s = 0.f;
#pragma unroll
  for (int a0i = 0; a0i < 2; ++a0i)
#pragma unroll
    for (int a1i = 0; a1i < 3; ++a1i)
#pragma unroll
      for (int a2i = 0; a2i < 3; ++a2i)
#pragma unroll
        for (int r4 = 0; r4 < 4; ++r4) s += acc[a0i][a1i][a2i][r4];
  scr[(size_t)h * 256 + tid] = s;
}

// ---------------- PROBE: 4x epilogue (4 distinct task decodes -> 693 MB streamed) ----------
__global__ __launch_bounds__(256, 1) void probe_epi4(float* __restrict__ scr) {
  __shared__ float outl[ND][W_N + 1];
  int h = blockIdx.x;
  int tid = threadIdx.x;
  int lane = tid & 63, w = tid >> 6;
  int p = w & 1, th = w >> 1;
  int m = lane & 15, kg = lane >> 4;
  f32x4 acc[2][3][3];
#pragma unroll
  for (int a0i = 0; a0i < 2; ++a0i)
#pragma unroll
    for (int a1i = 0; a1i < 3; ++a1i)
#pragma unroll
      for (int a2i = 0; a2i < 3; ++a2i)
        acc[a0i][a1i][a2i] = {(float)(tid + a0i), (float)a1i, (float)a2i, 1.0f};
  for (int ep = 0; ep < 4; ++ep) {
    int l = ((h & 7) * 672 + (h >> 3) + 1344 * ep) % 5376;
    int c = l / 7, q = l - 7 * c;
    int b = c / 96, i0 = c - 96 * b;
    int gidx = 6 - q;
    int i = i0 + 6 * q; if (i >= H_N) i -= H_N;
    int dyb = gidx * 3;
#pragma unroll
    for (int g = 0; g < 3; ++g) {
      __syncthreads();
#pragma unroll
      for (int tt = 0; tt < 2; ++tt) {
        int t = 2 * th + tt;
#pragma unroll
        for (int dl = 0; dl < 3; ++dl) {
#pragma unroll
          for (int r = 0; r < 4; ++r) {
            int a_ = kg * 4 + r;
            int dxi = 16 * dl + m - a_;
            if (dxi >= 0 && dxi <= 20) {
              int j = 2 * (16 * t + a_) + p;
              outl[dxi][j] = acc[tt][g][dl][r];
            }
          }
        }
      }
      __syncthreads();
      int dyi = dyb + g;
      size_t obase = ((size_t)(b * NK + dyi * ND) * H_N + i) * W_N;
      for (int idx = tid; idx < ND * W_N; idx += 256) {
        int dxi = idx >> 7, j = idx & 127;
        scr[obase + (size_t)dxi * (H_N * W_N) + j] = outl[dxi][j];
      }
    }
  }
}

// ---------------- PROBE: pure-MFMA clock read (81 us @ 2.4 GHz, 4 waves/SIMD) ----------------
__global__ __launch_bounds__(256) void probe_mfma(float* __restrict__ scr) {
  int tid = threadIdx.x;
  short8 a, bb;
#pragma unroll
  for (int k = 0; k < 8; ++k) { a[k] = (short)(tid + k); bb[k] = (short)(tid * 3 + k); }
  f32x4 acc[8];
#pragma unroll
  for (int k = 0; k < 8; ++k) acc[k] = {0.f, 0.f, 0.f, 0.f};
  for (int it = 0; it < 1250; ++it) {
#pragma unroll
    for (int k = 0; k < 8; ++k) acc[k] = MF(a, bb, acc[k]);
  }
  float s = 0.f;
#pragma unroll
  for (int k = 0; k < 8; ++k)
#pragma unroll
    for (int r = 0; r < 4; ++r) s += acc[k][r];
  scr[(size_t)blockIdx.x * 256 + tid] = s;
}

// ---------------- fallback (only if workspace too small) ----------------
__global__ void corr_naive(const float* __restrict__ in1, const float* __restrict__ in2,
                           float* __restrict__ out) {
  size_t o = (size_t)blockIdx.x * 256 + threadIdx.x;
  const size_t total = (size_t)B_N * NK * H_N * W_N;
  if (o >= total) return;
  int j = o & 127;
  int i = (int)((o >> 7) % H_N);
  int k = (int)((o / ((size_t)H_N * W_N)) % NK);
  int b = (int)(o / ((size_t)NK * H_N * W_N));
  int dyi = k / ND, dxi = k % ND;
  int y = i + 2 * dyi - 20, x = j + 2 * dxi - 20;
  float s = 0.f;
  if ((unsigned)y < (unsigned)H_N && (unsigned)x < (unsigned)W_N) {
    const float* p1 = in1 + ((size_t)b * C_N * H_N + i) * W_N + j;
    const float* p2 = in2 + ((size_t)b * C_N * H_N + y) * W_N + x;
    for (int c = 0; c < C_N; ++c)
      s += p1[(size_t)c * H_N * W_N] * p2[(size_t)c * H_N * W_N];
  }
  out[o] = s;
}

extern "C" void kernel_launch(void* const* d_in, const int* in_sizes, int n_in,
                              void* d_out, int out_size, void* d_ws, size_t ws_size,
                              hipStream_t stream) {
  const float* in1 = (const float*)d_in[0];
  const float* in2 = (const float*)d_in[1];
  float* out = (float*)d_out;

  const size_t A_BYTES = (size_t)6144 * 8192;      // 50,331,648
  const size_t B_BYTES = (size_t)6144 * 12288;     // 75,497,472
  const size_t SCR_BYTES = (size_t)768 * NK * W_N * 4;  // 173,408,256
  if (ws_size < A_BYTES + B_BYTES) {
    size_t total = (size_t)B_N * NK * H_N * W_N;
    corr_naive<<<(int)((total + 255) / 256), 256, 0, stream>>>(in1, in2, out);
    return;
  }
  unsigned short* Apre = (unsigned short*)d_ws;
  unsigned short* Bpre = (unsigned short*)((char*)d_ws + A_BYTES);

  prep<<<12288, 256, 0, stream>>>(in1, in2, Apre, Bpre);
  corr_fused<<<5376, 256, 0, stream>>>(Apre, Bpre, out);

  // amplified diagnostic probes (workspace-only writes; output above stays correct)
  if (ws_size >= A_BYTES + B_BYTES + SCR_BYTES) {
    float* scr = (float*)((char*)d_ws + A_BYTES + B_BYTES);
    probe_k4<<<5376, 256, 0, stream>>>(Apre, Bpre, scr);
    probe_epi4<<<5376, 256, 0, stream>>>(scr);
    probe_mfma<<<1024, 256, 0, stream>>>(scr);
  }
}

// Round 12
// 216.168 us; speedup vs baseline: 4.3706x; 4.3706x over previous
//
#include <hip/hip_runtime.h>
#include <stdint.h>

#define B_N   8
#define C_N   256
#define H_N   96
#define W_N   128
#define NCK   8          // C_N / 32
#define ND    21
#define NK    (ND * ND)  // 441

typedef __attribute__((ext_vector_type(8))) short short8;
typedef __attribute__((ext_vector_type(4))) float f32x4;

__device__ __forceinline__ uint32_t f2bf(float f) {
  uint32_t u = __builtin_bit_cast(uint32_t, f);
  return (u + 0x7fffu + ((u >> 16) & 1u)) >> 16;   // RNE
}
__device__ __forceinline__ uint32_t packbf(float lo, float hi) {
  return f2bf(lo) | (f2bf(hi) << 16);
}
__device__ __forceinline__ void async16(void* lds_dst, const void* gsrc) {
  __builtin_amdgcn_global_load_lds(
      (const __attribute__((address_space(1))) void*)gsrc,
      (__attribute__((address_space(3))) void*)lds_dst, 16, 0, 0);
}

// ---------------- merged prepass: fp32 NCHW -> bf16 fragment-linear layouts ----------------
// Apre per (bi,ck): 8 KB.  byte = tp*1024 + lane*16 ; tp = t*2+p ; lane = m+16kg
// Bpre per (by,ck): 12 KB. byte = sp*1024 + lane*16 ; sp = s*2+p ; x = 32s+2m-20+p, halo zeroed
__global__ __launch_bounds__(256) void prep(const float* __restrict__ in1,
                                            const float* __restrict__ in2,
                                            unsigned short* __restrict__ Apre,
                                            unsigned short* __restrict__ Bpre) {
  __shared__ float tile[32][W_N + 1];
  int blk = blockIdx.x;
  bool isA = blk < 6144;
  int rblk = isA ? blk : blk - 6144;
  int ck = rblk & 7, bi = rblk >> 3;
  int b = bi / H_N, row = bi % H_N;
  const float* src = (isA ? in1 : in2) + ((size_t)(b * C_N + ck * 32) * H_N + row) * W_N;
  int tid = threadIdx.x;
  for (int idx = tid; idx < 32 * W_N; idx += 256) {
    int c = idx >> 7, j = idx & 127;
    tile[c][j] = src[(size_t)c * (H_N * W_N) + j];
  }
  __syncthreads();
  if (isA) {
    uint32_t* dst = (uint32_t*)Apre + (size_t)rblk * 2048;
    for (int q = tid; q < 2048; q += 256) {
      int e2 = q & 3, ln = (q >> 2) & 63, tp = q >> 8;
      int t = tp >> 1, p = tp & 1;
      int m = ln & 15, kg = ln >> 4;
      int c0 = kg * 8 + 2 * e2;
      int j = 32 * t + 2 * m + p;
      dst[q] = packbf(tile[c0][j], tile[c0 + 1][j]);
    }
  } else {
    uint32_t* dst = (uint32_t*)Bpre + (size_t)rblk * 3072;
    for (int q = tid; q < 3072; q += 256) {
      int e2 = q & 3, ln = (q >> 2) & 63, sp = q >> 8;
      int s = sp >> 1, p = sp & 1;
      int m = ln & 15, kg = ln >> 4;
      int c0 = kg * 8 + 2 * e2;
      int x = 32 * s + 2 * m - 20 + p;
      dst[q] = ((unsigned)x < 128u) ? packbf(tile[c0][x], tile[c0 + 1][x]) : 0u;
    }
  }
}

#define MF(a, b, c) __builtin_amdgcn_mfma_f32_16x16x32_bf16(a, b, c, 0, 0, 0)

// issue this wave's 5 fills (1 KB each) for chunk CK into buffer BUF
#define STAGE(CK, BUF) do {                                                       \
  _Pragma("unroll")                                                               \
  for (int r_ = 0; r_ < 5; ++r_)                                                  \
    async16(lds + ((BUF) ? fdst1[r_] : fdst0[r_]),                                \
            fsrc[r_] + (size_t)(CK) * fstr[r_]);                                  \
} while (0)

// one K=32 chunk. Single barrier: each wave's vmcnt(0) certifies ITS fills for CK
// landed; the barrier then makes all fills visible AND certifies every wave finished
// reading the other buffer (its k-1 compute) -> safe to stage k+1 into it. Fills for
// k+1 are issued BEFORE compute k, so their latency hides under ds_read+MFMA.
#define CHUNK(CK, BUFOFF, DOSTAGE, STCK, STBUF) do {                              \
  asm volatile("s_waitcnt vmcnt(0)" ::: "memory");                                \
  __builtin_amdgcn_s_barrier();                                                   \
  __builtin_amdgcn_sched_barrier(0);                                              \
  if (DOSTAGE) STAGE(STCK, STBUF);                                                \
  __builtin_amdgcn_sched_barrier(0);                                              \
  if (act) {                                                                      \
    const char* bc_ = lds + (BUFOFF);                                             \
    short8 a0 = *(const short8*)(bc_ + aoff);                                     \
    short8 a1 = *(const short8*)(bc_ + aoff + 2048);                              \
    short8 a2 = *(const short8*)(bc_ + aoff + 4096);                              \
    _Pragma("unroll")                                                             \
    for (int g_ = 0; g_ < 3; ++g_) {                                              \
      const char* bb_ = bc_ + boff + g_ * 12288;                                  \
      short8 b0 = *(const short8*)(bb_);                                          \
      short8 b1 = *(const short8*)(bb_ + 2048);                                   \
      short8 b2 = *(const short8*)(bb_ + 4096);                                   \
      if (th == 0) {  /* (t,s): (0,0),(0,1),(1,1),(0,2),(1,2),(2,2) */            \
        acc[g_][0] = MF(a0, b0, acc[g_][0]);                                      \
        acc[g_][1] = MF(a0, b1, acc[g_][1]);                                      \
        acc[g_][2] = MF(a1, b1, acc[g_][2]);                                      \
        acc[g_][3] = MF(a0, b2, acc[g_][3]);                                      \
        acc[g_][4] = MF(a1, b2, acc[g_][4]);                                      \
        acc[g_][5] = MF(a2, b2, acc[g_][5]);                                      \
      } else {        /* (t,s): (1,3),(2,3),(2,4),(3,3),(3,4),(3,5) */            \
        acc[g_][0] = MF(b0, a0, acc[g_][0]);                                      \
        acc[g_][1] = MF(b0, a1, acc[g_][1]);                                      \
        acc[g_][2] = MF(b1, a1, acc[g_][2]);                                      \
        acc[g_][3] = MF(b0, a2, acc[g_][3]);                                      \
        acc[g_][4] = MF(b1, a2, acc[g_][4]);                                      \
        acc[g_][5] = MF(b2, a2, acc[g_][5]);                                      \
      }                                                                           \
    }                                                                             \
  }                                                                               \
} while (0)

// ---------------- main: 3-el chain block, full-LDS frags, fills-overlap-compute ----------
// Chain Y: els share B rows {Y, Y+2, Y+4}. 12 waves = (el, p, th).
// LDS: buf0 [0,61440) = A 3el x 8KB + B 3k x 12KB ; buf1 [61440,122880) ; pad [122880,123904).
// Per chunk: 60 fills (5/wave) issued pre-compute; 12 ds_read_b128 + 18 MFMA; ONE s_barrier.
__global__ __launch_bounds__(768, 3) void corr_main(const unsigned short* __restrict__ Apre,
                                                    const unsigned short* __restrict__ Bpre,
                                                    float* __restrict__ out) {
  __shared__ __align__(16) char lds[123904];

  int h = blockIdx.x;
  int b = h & 7, blk = h >> 3;          // one batch image per XCD; blk ascending = Y ascending
  int Y, pos;
  if (blk < 18)       { Y = blk - 20;                pos = 0; }
  else if (blk < 54)  { int t = blk - 18;  Y = -2 + (t >> 1); pos = t & 1; }
  else if (blk < 234) { int t = blk - 54;  Y = 16 + t / 3;    pos = t % 3; }
  else if (blk < 270) { int t = blk - 234; Y = 76 + (t >> 1); pos = t & 1; }
  else                { Y = 94 + (blk - 270);        pos = 0; }
  int g_min = (Y > 75) ? (Y - 70) / 6 : 0;
  int g_max = (Y + 20) / 6; if (g_max > 6) g_max = 6;

  int tid = threadIdx.x;
  int lane = tid & 63, w = tid >> 6;    // 12 waves: (el, p, th)
  int el = w >> 2, sub = w & 3;
  int p = sub & 1, th = sub >> 1;
  int m = lane & 15, kg = lane >> 4;

  int gidx = g_min + pos * 3 + el;
  bool act = gidx <= g_max;
  int i_el = Y + 20 - 6 * gidx;
  int dyb = 3 * gidx;

  // ---- fill assignments: 60 units = A 24 (el,tp) + B 36 (k,sp); unit u = w*5 + r
  int fdst0[5], fdst1[5], fstr[5];
  const char* fsrc[5];
#pragma unroll
  for (int r = 0; r < 5; ++r) {
    int u = w * 5 + r;
    if (u < 24) {
      int ael = u >> 3, tp = u & 7;
      int gi = g_min + pos * 3 + ael;
      int ia = Y + 20 - 6 * gi; ia = ia < 0 ? 0 : (ia > 95 ? 95 : ia);   // clamp for inactive el
      int dst = ael * 8192 + tp * 1024 + lane * 16;
      fdst0[r] = dst; fdst1[r] = dst + 61440;
      fsrc[r] = (const char*)Apre + ((size_t)(b * H_N + ia) * NCK) * 8192 + tp * 1024 + lane * 16;
      fstr[r] = 8192;
    } else {
      int v = u - 24, k = v / 12, sp = v - k * 12;
      int y = Y + 2 * k;
      bool vy = (unsigned)y < (unsigned)H_N;
      int dst = vy ? (24576 + k * 12288 + sp * 1024 + lane * 16) : (122880 + lane * 16);
      fdst0[r] = dst; fdst1[r] = vy ? (dst + 61440) : dst;
      fsrc[r] = (const char*)Bpre + ((size_t)(b * H_N + (vy ? y : 0)) * NCK) * 12288
                + sp * 1024 + lane * 16;
      fstr[r] = 12288;
    }
  }

  // ---- zero invalid B rows in both buffers (their fills are redirected to pad)
  {
    short8 z = {};
#pragma unroll
    for (int k = 0; k < 3; ++k) {
      int y = Y + 2 * k;
      if ((unsigned)y >= (unsigned)H_N) {
        *(short8*)(lds + 24576 + k * 12288 + tid * 16) = z;
        *(short8*)(lds + 61440 + 24576 + k * 12288 + tid * 16) = z;
      }
    }
  }
  asm volatile("s_waitcnt lgkmcnt(0)" ::: "memory");

  f32x4 acc[3][6];
#pragma unroll
  for (int gi = 0; gi < 3; ++gi)
#pragma unroll
    for (int ki = 0; ki < 6; ++ki) acc[gi][ki] = {0.f, 0.f, 0.f, 0.f};

  // frag read bases (buffer-relative): th selects the t/s band halves
  int aoff = el * 8192 + th * 2048 + p * 1024 + lane * 16;           // A t = th+{0,1,2}
  int boff = 24576 + th * 6144 + p * 1024 + lane * 16;               // B s = 3th+{0,1,2}

  STAGE(0, 0);
  CHUNK(0, 0,     1, 1, 1);
  CHUNK(1, 61440, 1, 2, 0);
  CHUNK(2, 0,     1, 3, 1);
  CHUNK(3, 61440, 1, 4, 0);
  CHUNK(4, 0,     1, 5, 1);
  CHUNK(5, 61440, 1, 6, 0);
  CHUNK(6, 0,     1, 7, 1);
  CHUNK(7, 61440, 0, 0, 0);
  __syncthreads();               // all LDS frag reads done before epilogue reuse

  // ---- epilogue: per-el band-extract via LDS, coalesced stores (validated R8)
  float* outl = (float*)(lds + el * 11072);   // [21][129] f32 per el, 3*11072 < 61440
  int gt = sub * 64 + lane;                   // [0,256) within el-group
#pragma unroll
  for (int g = 0; g < 3; ++g) {
    if (act) {
#pragma unroll
      for (int k = 0; k < 6; ++k) {
        const int T0c[6] = {0, 0, 1, 0, 1, 2}, S0c[6] = {0, 1, 1, 2, 2, 2};
        const int T1c[6] = {1, 2, 2, 3, 3, 3}, S1c[6] = {3, 3, 4, 3, 4, 5};
        int T = th ? T1c[k] : T0c[k];
        int S = th ? S1c[k] : S0c[k];
#pragma unroll
        for (int r = 0; r < 4; ++r) {
          int a_ = kg * 4 + r;
          int dxi = 16 * (S - T) + (th ? (a_ - m) : (m - a_));
          if (dxi >= 0 && dxi <= 20) {
            int j = 2 * (16 * T + (th ? m : a_)) + p;
            outl[dxi * 129 + j] = acc[g][k][r];
          }
        }
      }
    }
    __syncthreads();
    if (act) {
      int dyi = dyb + g;
      size_t obase = ((size_t)(b * NK + dyi * ND) * H_N + i_el) * W_N;
      for (int idx = gt; idx < ND * W_N; idx += 256) {
        int dxi = idx >> 7, j = idx & 127;
        out[obase + (size_t)dxi * (H_N * W_N) + j] = outl[dxi * 129 + j];
      }
    }
    __syncthreads();
  }
}

// ---------------- fallback (only if workspace too small) ----------------
__global__ void corr_naive(const float* __restrict__ in1, const float* __restrict__ in2,
                           float* __restrict__ out) {
  size_t o = (size_t)blockIdx.x * 256 + threadIdx.x;
  const size_t total = (size_t)B_N * NK * H_N * W_N;
  if (o >= total) return;
  int j = o & 127;
  int i = (int)((o >> 7) % H_N);
  int k = (int)((o / ((size_t)H_N * W_N)) % NK);
  int b = (int)(o / ((size_t)NK * H_N * W_N));
  int dyi = k / ND, dxi = k % ND;
  int y = i + 2 * dyi - 20, x = j + 2 * dxi - 20;
  float s = 0.f;
  if ((unsigned)y < (unsigned)H_N && (unsigned)x < (unsigned)W_N) {
    const float* p1 = in1 + ((size_t)b * C_N * H_N + i) * W_N + j;
    const float* p2 = in2 + ((size_t)b * C_N * H_N + y) * W_N + x;
    for (int c = 0; c < C_N; ++c)
      s += p1[(size_t)c * H_N * W_N] * p2[(size_t)c * H_N * W_N];
  }
  out[o] = s;
}

extern "C" void kernel_launch(void* const* d_in, const int* in_sizes, int n_in,
                              void* d_out, int out_size, void* d_ws, size_t ws_size,
                              hipStream_t stream) {
  const float* in1 = (const float*)d_in[0];
  const float* in2 = (const float*)d_in[1];
  float* out = (float*)d_out;

  const size_t A_BYTES = (size_t)6144 * 8192;    // 50,331,648
  const size_t B_BYTES = (size_t)6144 * 12288;   // 75,497,472
  if (ws_size < A_BYTES + B_BYTES) {
    size_t total = (size_t)B_N * NK * H_N * W_N;
    corr_naive<<<(int)((total + 255) / 256), 256, 0, stream>>>(in1, in2, out);
    return;
  }
  unsigned short* Apre = (unsigned short*)d_ws;
  unsigned short* Bpre = (unsigned short*)((char*)d_ws + A_BYTES);

  prep<<<12288, 256, 0, stream>>>(in1, in2, Apre, Bpre);
  corr_main<<<2304, 768, 0, stream>>>(Apre, Bpre, out);
}

// Round 13
// 208.149 us; speedup vs baseline: 4.5389x; 1.0385x over previous
//
#include <hip/hip_runtime.h>
#include <stdint.h>

#define B_N   8
#define C_N   256
#define H_N   96
#define W_N   128
#define NCK   8          // C_N / 32
#define ND    21
#define NK    (ND * ND)  // 441

typedef __attribute__((ext_vector_type(8))) short short8;
typedef __attribute__((ext_vector_type(4))) float f32x4;

// 12-KB zero block (.bss) for OOB dy rows
__device__ char zchunk[12288];

__device__ __forceinline__ uint32_t f2bf(float f) {
  uint32_t u = __builtin_bit_cast(uint32_t, f);
  return (u + 0x7fffu + ((u >> 16) & 1u)) >> 16;   // RNE
}
__device__ __forceinline__ uint32_t packbf(float lo, float hi) {
  return f2bf(lo) | (f2bf(hi) << 16);
}

// ---------------- merged prepass: fp32 NCHW -> bf16 fragment-linear layouts ----------------
__global__ __launch_bounds__(256) void prep(const float* __restrict__ in1,
                                            const float* __restrict__ in2,
                                            unsigned short* __restrict__ Apre,
                                            unsigned short* __restrict__ Bpre) {
  __shared__ float tile[32][W_N + 1];
  int blk = blockIdx.x;
  bool isA = blk < 6144;
  int rblk = isA ? blk : blk - 6144;
  int ck = rblk & 7, bi = rblk >> 3;
  int b = bi / H_N, row = bi % H_N;
  const float* src = (isA ? in1 : in2) + ((size_t)(b * C_N + ck * 32) * H_N + row) * W_N;
  int tid = threadIdx.x;
  for (int idx = tid; idx < 32 * W_N; idx += 256) {
    int c = idx >> 7, j = idx & 127;
    tile[c][j] = src[(size_t)c * (H_N * W_N) + j];
  }
  __syncthreads();
  if (isA) {
    uint32_t* dst = (uint32_t*)Apre + (size_t)rblk * 2048;
    for (int q = tid; q < 2048; q += 256) {
      int e2 = q & 3, ln = (q >> 2) & 63, tp = q >> 8;
      int t = tp >> 1, p = tp & 1;
      int m = ln & 15, kg = ln >> 4;
      int c0 = kg * 8 + 2 * e2;
      int j = 32 * t + 2 * m + p;
      dst[q] = packbf(tile[c0][j], tile[c0 + 1][j]);
    }
  } else {
    uint32_t* dst = (uint32_t*)Bpre + (size_t)rblk * 3072;
    for (int q = tid; q < 3072; q += 256) {
      int e2 = q & 3, ln = (q >> 2) & 63, sp = q >> 8;
      int s = sp >> 1, p = sp & 1;
      int m = ln & 15, kg = ln >> 4;
      int c0 = kg * 8 + 2 * e2;
      int x = 32 * s + 2 * m - 20 + p;
      dst[q] = ((unsigned)x < 128u) ? packbf(tile[c0][x], tile[c0 + 1][x]) : 0u;
    }
  }
}

// ---- fragment set: one chunk, disjoint-th bands: 3 A + 9 B = 12 frags (48 VGPR) ----
#define DECL_FRAGS(F) short8 F##_a0, F##_a1, F##_a2, \
                             F##_b00, F##_b01, F##_b02, \
                             F##_b10, F##_b11, F##_b12, \
                             F##_b20, F##_b21, F##_b22

#define LOADF(F, CK) do {                                                        \
  F##_a0  = *(const short8*)(Ap  + (size_t)(CK) * 8192);                         \
  F##_a1  = *(const short8*)(Ap  + (size_t)(CK) * 8192 + 2048);                  \
  F##_a2  = *(const short8*)(Ap  + (size_t)(CK) * 8192 + 4096);                  \
  F##_b00 = *(const short8*)(Bp0 + (size_t)(CK) * bstr0);                        \
  F##_b01 = *(const short8*)(Bp0 + (size_t)(CK) * bstr0 + 2048);                 \
  F##_b02 = *(const short8*)(Bp0 + (size_t)(CK) * bstr0 + 4096);                 \
  F##_b10 = *(const short8*)(Bp1 + (size_t)(CK) * bstr1);                        \
  F##_b11 = *(const short8*)(Bp1 + (size_t)(CK) * bstr1 + 2048);                 \
  F##_b12 = *(const short8*)(Bp1 + (size_t)(CK) * bstr1 + 4096);                 \
  F##_b20 = *(const short8*)(Bp2 + (size_t)(CK) * bstr2);                        \
  F##_b21 = *(const short8*)(Bp2 + (size_t)(CK) * bstr2 + 2048);                 \
  F##_b22 = *(const short8*)(Bp2 + (size_t)(CK) * bstr2 + 4096);                 \
} while (0)

#define MF(a, b, c) __builtin_amdgcn_mfma_f32_16x16x32_bf16(a, b, c, 0, 0, 0)

// th0 pairs (t,s): (0,0),(0,1),(1,1),(0,2),(1,2),(2,2)  [A,B operand order]
#define COMPG0(F, G) do {                                                        \
  acc[G][0] = MF(F##_a0, F##_b##G##0, acc[G][0]);                                \
  acc[G][1] = MF(F##_a0, F##_b##G##1, acc[G][1]);                                \
  acc[G][2] = MF(F##_a1, F##_b##G##1, acc[G][2]);                                \
  acc[G][3] = MF(F##_a0, F##_b##G##2, acc[G][3]);                                \
  acc[G][4] = MF(F##_a1, F##_b##G##2, acc[G][4]);                                \
  acc[G][5] = MF(F##_a2, F##_b##G##2, acc[G][5]);                                \
} while (0)
// th1 pairs (t,s): (1,3),(2,3),(2,4),(3,3),(3,4),(3,5)  [B,A swapped — R8-validated]
#define COMPG1(F, G) do {                                                        \
  acc[G][0] = MF(F##_b##G##0, F##_a0, acc[G][0]);                                \
  acc[G][1] = MF(F##_b##G##0, F##_a1, acc[G][1]);                                \
  acc[G][2] = MF(F##_b##G##1, F##_a1, acc[G][2]);                                \
  acc[G][3] = MF(F##_b##G##0, F##_a2, acc[G][3]);                                \
  acc[G][4] = MF(F##_b##G##1, F##_a2, acc[G][4]);                                \
  acc[G][5] = MF(F##_b##G##2, F##_a2, acc[G][5]);                                \
} while (0)

#define COMPUTE(F) do {                                                          \
  if (th == 0) { COMPG0(F, 0); COMPG0(F, 1); COMPG0(F, 2); }                     \
  else         { COMPG1(F, 0); COMPG1(F, 1); COMPG1(F, 2); }                     \
} while (0)

#define SB() __builtin_amdgcn_sched_barrier(0)

// ---------------- main: direct-global, disjoint-th bands, pinned 2-deep pipeline ----------
__global__ __launch_bounds__(256, 1) void corr_main(const unsigned short* __restrict__ Apre,
                                                    const unsigned short* __restrict__ Bpre,
                                                    float* __restrict__ out) {
  __shared__ float outl[ND][W_N + 1];   // 10836 B epilogue buffer

  int h = blockIdx.x;
  int l = (h & 7) * 672 + (h >> 3);     // XCD-chunked remap (5376 = 8*672, bijective)
  int c = l / 7, q = l - 7 * c;         // chain keeps B rows identical across the 7 tasks
  int b = c / 96, i0 = c - 96 * b;
  int gidx = 6 - q;
  int i = i0 + 6 * q; if (i >= H_N) i -= H_N;
  int bi = b * H_N + i;
  int dyb = gidx * 3;

  int tid = threadIdx.x;
  int lane = tid & 63, w = tid >> 6;    // 4 waves: (parity p, band-half th)
  int p = w & 1, th = w >> 1;
  int m = lane & 15, kg = lane >> 4;

  f32x4 acc[3][6];                      // [g][pair]
#pragma unroll
  for (int gi = 0; gi < 3; ++gi)
#pragma unroll
    for (int ki = 0; ki < 6; ++ki) acc[gi][ki] = {0.f, 0.f, 0.f, 0.f};

  // A tiles: th0 -> t{0,1,2}, th1 -> t{1,2,3}; byte (2t+p)*1024, base = th*2048
  const char* Ap = (const char*)Apre + (size_t)bi * 65536
                   + th * 2048 + p * 1024 + lane * 16;
  // B tiles: th0 -> s{0,1,2}, th1 -> s{3,4,5}; byte (2s+p)*1024, base = th*6144
  const char* Bp0; const char* Bp1; const char* Bp2;
  int bstr0, bstr1, bstr2;
  {
    int y0 = i + 2 * dyb - 20;
#pragma unroll
    for (int g = 0; g < 3; ++g) {
      int y = y0 + 2 * g;
      bool v = (unsigned)y < (unsigned)H_N;
      const char* base = v ? (const char*)Bpre + (size_t)(b * H_N + y) * 98304
                           : (const char*)zchunk;
      const char* bp = base + th * 6144 + p * 1024 + lane * 16;
      int bs = v ? 12288 : 0;
      if (g == 0) { Bp0 = bp; bstr0 = bs; }
      else if (g == 1) { Bp1 = bp; bstr1 = bs; }
      else { Bp2 = bp; bstr2 = bs; }
    }
  }

  DECL_FRAGS(fA);
  DECL_FRAGS(fB);

  // 2-deep register pipeline over 8 chunks, slot boundaries pinned by SB()
  LOADF(fA, 0);
  LOADF(fB, 1);
  SB();
  COMPUTE(fA); LOADF(fA, 2); SB();
  COMPUTE(fB); LOADF(fB, 3); SB();
  COMPUTE(fA); LOADF(fA, 4); SB();
  COMPUTE(fB); LOADF(fB, 5); SB();
  COMPUTE(fA); LOADF(fA, 6); SB();
  COMPUTE(fB); LOADF(fB, 7); SB();
  COMPUTE(fA); SB();
  COMPUTE(fB);

  // ---- epilogue: band-extract via LDS (R8-validated T/S tables), coalesced stores
#pragma unroll
  for (int g = 0; g < 3; ++g) {
    __syncthreads();
    {
      const int T0c[6] = {0, 0, 1, 0, 1, 2}, S0c[6] = {0, 1, 1, 2, 2, 2};
      const int T1c[6] = {1, 2, 2, 3, 3, 3}, S1c[6] = {3, 3, 4, 3, 4, 5};
#pragma unroll
      for (int k = 0; k < 6; ++k) {
        int T = th ? T1c[k] : T0c[k];
        int S = th ? S1c[k] : S0c[k];
#pragma unroll
        for (int r = 0; r < 4; ++r) {
          int a_ = kg * 4 + r;
          int dxi = 16 * (S - T) + (th ? (a_ - m) : (m - a_));
          if (dxi >= 0 && dxi <= 20) {
            int j = 2 * (16 * T + (th ? m : a_)) + p;
            outl[dxi][j] = acc[g][k][r];
          }
        }
      }
    }
    __syncthreads();
    int dyi = dyb + g;
    size_t obase = ((size_t)(b * NK + dyi * ND) * H_N + i) * W_N;
    for (int idx = tid; idx < ND * W_N; idx += 256) {
      int dxi = idx >> 7, j = idx & 127;
      out[obase + (size_t)dxi * (H_N * W_N) + j] = outl[dxi][j];
    }
  }
}

// ---------------- fallback (only if workspace too small) ----------------
__global__ void corr_naive(const float* __restrict__ in1, const float* __restrict__ in2,
                           float* __restrict__ out) {
  size_t o = (size_t)blockIdx.x * 256 + threadIdx.x;
  const size_t total = (size_t)B_N * NK * H_N * W_N;
  if (o >= total) return;
  int j = o & 127;
  int i = (int)((o >> 7) % H_N);
  int k = (int)((o / ((size_t)H_N * W_N)) % NK);
  int b = (int)(o / ((size_t)NK * H_N * W_N));
  int dyi = k / ND, dxi = k % ND;
  int y = i + 2 * dyi - 20, x = j + 2 * dxi - 20;
  float s = 0.f;
  if ((unsigned)y < (unsigned)H_N && (unsigned)x < (unsigned)W_N) {
    const float* p1 = in1 + ((size_t)b * C_N * H_N + i) * W_N + j;
    const float* p2 = in2 + ((size_t)b * C_N * H_N + y) * W_N + x;
    for (int c = 0; c < C_N; ++c)
      s += p1[(size_t)c * H_N * W_N] * p2[(size_t)c * H_N * W_N];
  }
  out[o] = s;
}

extern "C" void kernel_launch(void* const* d_in, const int* in_sizes, int n_in,
                              void* d_out, int out_size, void* d_ws, size_t ws_size,
                              hipStream_t stream) {
  const float* in1 = (const float*)d_in[0];
  const float* in2 = (const float*)d_in[1];
  float* out = (float*)d_out;

  const size_t A_BYTES = (size_t)6144 * 8192;    // 50,331,648
  const size_t B_BYTES = (size_t)6144 * 12288;   // 75,497,472
  if (ws_size < A_BYTES + B_BYTES) {
    size_t total = (size_t)B_N * NK * H_N * W_N;
    corr_naive<<<(int)((total + 255) / 256), 256, 0, stream>>>(in1, in2, out);
    return;
  }
  unsigned short* Apre = (unsigned short*)d_ws;
  unsigned short* Bpre = (unsigned short*)((char*)d_ws + A_BYTES);

  prep<<<12288, 256, 0, stream>>>(in1, in2, Apre, Bpre);
  corr_main<<<5376, 256, 0, stream>>>(Apre, Bpre, out);
}